// Round 2
// baseline (16441.272 us; speedup 1.0000x reference)
//
#include <hip/hip_runtime.h>
#include <cstdint>

#define A_N 50000
#define E_N 1200000
#define T_N 2000000
#define G_N 500
#define U_N 64
#define RBF_N 48
#define NB 3

#define SCAN_CHUNK 2048  // 256 threads * 8 elems
#define TRI_CHUNKS ((E_N + SCAN_CHUNK - 1) / SCAN_CHUNK)

__device__ __forceinline__ float sigf(float x){ return 1.0f/(1.0f+__expf(-x)); }
__device__ __forceinline__ float siluf(float x){ return x/(1.0f+__expf(-x)); }

// LDS bond tile layout: transposed + XOR swizzle. k = feature (0..63), e = edge-in-wave.
__device__ __forceinline__ int sw(int k, int e){ return k*64 + (e ^ (k & 31)); }

// atom = emb[atom_types]   (A x 64)
__global__ void k_atom_init(const int* __restrict__ types, const float* __restrict__ emb,
                            float* __restrict__ atom){
  int idx = blockIdx.x*256 + threadIdx.x;
  int a = idx >> 6, u = idx & 63;
  atom[idx] = emb[types[a]*U_N + u];
}

// bond = silu(rbf @ bW + bb)   (E x 64)
__global__ void k_bond_init(const float* __restrict__ rbf, const float* __restrict__ bW,
                            const float* __restrict__ bb, float* __restrict__ bond){
  int idx = blockIdx.x*256 + threadIdx.x;
  int e = idx >> 6, u = idx & 63;
  float acc = bb[u];
  acc += rbf[e*3+0]*bW[0*U_N+u];
  acc += rbf[e*3+1]*bW[1*U_N+u];
  acc += rbf[e*3+2]*bW[2*U_N+u];
  bond[idx] = siluf(acc);
}

// ---- CSR build for triples grouped by tb0 (topology fixed across blocks; built once) ----

__global__ void k_hist_tri(const int* __restrict__ tbi, int* __restrict__ hist){
  int t = blockIdx.x*256 + threadIdx.x;
  if (t < T_N) atomicAdd(&hist[tbi[2*t]], 1);
}

// per-chunk exclusive scan (256 thr x 8 elems), chunk totals -> sums[]
__global__ void k_scan1(const int* __restrict__ in, int* __restrict__ out,
                        int* __restrict__ sums, int n){
  __shared__ int sdata[256];
  int base = blockIdx.x*SCAN_CHUNK;
  int tid = threadIdx.x;
  int v[8]; int s = 0;
  #pragma unroll
  for (int k=0;k<8;++k){ int i = base + tid*8 + k; v[k] = (i<n) ? in[i] : 0; s += v[k]; }
  sdata[tid] = s; __syncthreads();
  #pragma unroll
  for (int off=1; off<256; off<<=1){
    int t = (tid>=off) ? sdata[tid-off] : 0;
    __syncthreads();
    sdata[tid] += t;
    __syncthreads();
  }
  int run = (tid==0) ? 0 : sdata[tid-1];
  if (tid==255) sums[blockIdx.x] = sdata[255];
  #pragma unroll
  for (int k=0;k<8;++k){ int i = base + tid*8 + k; if (i<n) out[i] = run; run += v[k]; }
}

// serial exclusive scan of chunk sums (runs once, few hundred elems); total -> *total
__global__ void k_scan2(int* __restrict__ sums, int nchunks, int* __restrict__ total){
  if (blockIdx.x==0 && threadIdx.x==0){
    int acc = 0;
    for (int c=0;c<nchunks;++c){ int v = sums[c]; sums[c] = acc; acc += v; }
    *total = acc;
  }
}

__global__ void k_scan3(int* __restrict__ out, const int* __restrict__ sums, int n){
  int i = blockIdx.x*256 + threadIdx.x;
  if (i < n) out[i] += sums[i / SCAN_CHUNK];
}

// scatter: perm[pos] = t, ends[pos] = dst[tb1[t]], grouped by tb0
// (end_atom computed inline; no separate k_end pass / buffer)
__global__ void k_scatter_tri(const int* __restrict__ tbi, const int* __restrict__ bai,
                              const int* __restrict__ offs, int* __restrict__ cursor,
                              int* __restrict__ perm, int* __restrict__ ends){
  int t = blockIdx.x*256 + threadIdx.x;
  if (t < T_N){
    int b = tbi[2*t];
    int pos = offs[b] + atomicAdd(&cursor[b], 1);
    perm[pos] = t;
    ends[pos] = bai[2*tbi[2*t+1]+1];
  }
}

// agg[e] = sum over triples with tb0==e of three_basis[t] * tuo[end_atom[t]]
// atomic-free segmented reduction; also replaces the agg memset (writes every element).
// thread per (e, q) with q indexing float4 chunks of the 48-wide row.
__global__ void k_triple_s(const float* __restrict__ tb, const int* __restrict__ perm,
                           const int* __restrict__ ends, const float* __restrict__ tuo,
                           const int* __restrict__ offs, float* __restrict__ agg){
  int idx = blockIdx.x*256 + threadIdx.x;      // E_N*12 total, divisible by 256
  int e = idx / 12, q = idx - e*12;
  int j0 = offs[e], j1 = offs[e+1];
  float4 acc = make_float4(0.f,0.f,0.f,0.f);
  for (int j=j0; j<j1; ++j){
    int t  = perm[j];                          // broadcast across the 12 lanes of e
    int ea = ends[j];
    float4 b = *(const float4*)(tb  + (size_t)t *48 + q*4);
    float4 w = *(const float4*)(tuo + (size_t)ea*48 + q*4);
    acc.x = fmaf(b.x, w.x, acc.x);
    acc.y = fmaf(b.y, w.y, acc.y);
    acc.z = fmaf(b.z, w.z, acc.z);
    acc.w = fmaf(b.w, w.w, acc.w);
  }
  *(float4*)(agg + (size_t)e*48 + q*4) = acc;
}

// tuo = sigmoid(atom @ tuW + tub)   (A x 48)
__global__ void k_tu(const float* __restrict__ atom, const float* __restrict__ tuW,
                     const float* __restrict__ tub, float* __restrict__ tuo){
  int idx = blockIdx.x*256 + threadIdx.x;
  int a = idx / 48, r = idx - a*48;
  const float* ar = atom + a*U_N;
  float acc = tub[r];
  #pragma unroll
  for (int v=0; v<U_N; ++v) acc += ar[v]*tuW[v*48+r];
  tuo[idx] = sigf(acc);
}

// accumulate an 8-wide K chunk into 32 outputs (x2 matrices). c stays in VGPRs
// (k fully unrolled); weight addresses are wave-uniform -> scalar loads broadcast.
__device__ __forceinline__ void accum8(const float* __restrict__ W1, const float* __restrict__ W2,
                                       int kb, int ub, const float (&c)[8],
                                       float (&acc1)[32], float (&acc2)[32]){
  #pragma unroll
  for (int k=0;k<8;++k){
    const float cv = c[k];
    const float* w1 = W1 + (size_t)(kb+k)*64 + ub;
    const float* w2 = W2 + (size_t)(kb+k)*64 + ub;
    #pragma unroll
    for (int u=0;u<32;++u){
      acc1[u] = fmaf(cv, w1[u], acc1[u]);
      acc2[u] = fmaf(cv, w2[u], acc2[u]);
    }
  }
}

// Fused per-edge: bond += tf(agg); bond += gb(cat); msg = ga(bond); atom_next += msg
__global__ __launch_bounds__(128) void k_edge(
    const float* __restrict__ agg, float* __restrict__ bond,
    const float* __restrict__ atomc, float* __restrict__ atomn,
    const int* __restrict__ bai,
    const float* __restrict__ tfW1, const float* __restrict__ tfb1,
    const float* __restrict__ tfW2, const float* __restrict__ tfb2,
    const float* __restrict__ gbW1, const float* __restrict__ gbb1,
    const float* __restrict__ gbW2, const float* __restrict__ gbb2,
    const float* __restrict__ gaW1, const float* __restrict__ gab1,
    const float* __restrict__ gaW2, const float* __restrict__ gab2)
{
  __shared__ float s_all[2*64*64];
  const int lane  = threadIdx.x & 63;
  const int w     = threadIdx.x >> 6;
  float* sb = s_all + w*4096;
  const int ebase = blockIdx.x*128 + w*64;
  const int e     = ebase + lane;

  // stage bond tile: coalesced 256B row reads, swizzled transposed LDS writes
  #pragma unroll 1
  for (int i=0;i<64;++i)
    sb[sw(lane, i)] = bond[(size_t)(ebase+i)*64 + lane];

  const float* aggr = agg + (size_t)e*48;

  // ---- phase 1: tf ----
  #pragma unroll 1
  for (int ug=0; ug<2; ++ug){
    const int ub = ug*32;
    float acc1[32], acc2[32];
    #pragma unroll
    for (int u=0;u<32;++u){ acc1[u] = tfb1[ub+u]; acc2[u] = tfb2[ub+u]; }
    #pragma unroll 1
    for (int kc=0;kc<6;++kc){
      float c[8];
      const float4* p = (const float4*)(aggr + kc*8);
      float4 v0 = p[0], v1 = p[1];
      c[0]=v0.x;c[1]=v0.y;c[2]=v0.z;c[3]=v0.w;c[4]=v1.x;c[5]=v1.y;c[6]=v1.z;c[7]=v1.w;
      accum8(tfW1, tfW2, kc*8, ub, c, acc1, acc2);
    }
    #pragma unroll
    for (int u=0;u<32;++u)
      sb[sw(ub+u, lane)] += siluf(acc1[u])*sigf(acc2[u]);
  }

  // ---- phase 2: gb (cat = [atom[src], atom[dst], bond_new]) ----
  const int src = bai[2*e], dst = bai[2*e+1];
  const float* srow = atomc + (size_t)src*64;
  const float* drow = atomc + (size_t)dst*64;
  float res0[32];                       // ug0 results stashed so ug1 still sees old bond in LDS
  #pragma unroll
  for (int ug=0; ug<2; ++ug){
    const int ub = ug*32;
    float acc1[32], acc2[32];
    #pragma unroll
    for (int u=0;u<32;++u){ acc1[u] = gbb1[ub+u]; acc2[u] = gbb2[ub+u]; }
    // segments 0,1: gathered atom rows (k 0..63 and 64..127)
    #pragma unroll 1
    for (int s=0;s<2;++s){
      const float* row = s ? drow : srow;
      const int kb = s*64;
      #pragma unroll 1
      for (int kc=0;kc<8;++kc){
        float c[8];
        const float4* p = (const float4*)(row + kc*8);
        float4 v0 = p[0], v1 = p[1];
        c[0]=v0.x;c[1]=v0.y;c[2]=v0.z;c[3]=v0.w;c[4]=v1.x;c[5]=v1.y;c[6]=v1.z;c[7]=v1.w;
        accum8(gbW1, gbW2, kb+kc*8, ub, c, acc1, acc2);
      }
    }
    // segment 2: bond_new from LDS (k 128..191)
    #pragma unroll 1
    for (int kc=0;kc<8;++kc){
      float c[8];
      #pragma unroll
      for (int j=0;j<8;++j) c[j] = sb[sw(kc*8+j, lane)];
      accum8(gbW1, gbW2, 128+kc*8, ub, c, acc1, acc2);
    }
    if (ug==0){
      #pragma unroll
      for (int u=0;u<32;++u)
        res0[u] = sb[sw(u, lane)] + siluf(acc1[u])*sigf(acc2[u]);
    } else {
      #pragma unroll
      for (int u=0;u<32;++u)
        sb[sw(32+u, lane)] += siluf(acc1[u])*sigf(acc2[u]);
      #pragma unroll
      for (int u=0;u<32;++u)
        sb[sw(u, lane)] = res0[u];
    }
  }

  // ---- phase 3: ga -> msg -> atomic accumulate into atom_next ----
  float* arow = atomn + (size_t)dst*64;
  #pragma unroll 1
  for (int ug=0; ug<2; ++ug){
    const int ub = ug*32;
    float acc1[32], acc2[32];
    #pragma unroll
    for (int u=0;u<32;++u){ acc1[u] = gab1[ub+u]; acc2[u] = gab2[ub+u]; }
    #pragma unroll 1
    for (int kc=0;kc<8;++kc){
      float c[8];
      #pragma unroll
      for (int j=0;j<8;++j) c[j] = sb[sw(kc*8+j, lane)];
      accum8(gaW1, gaW2, kc*8, ub, c, acc1, acc2);
    }
    #pragma unroll
    for (int u=0;u<32;++u)
      atomicAdd(arow + ub + u, siluf(acc1[u])*sigf(acc2[u]));
  }

  // final bond store: coalesced
  #pragma unroll 1
  for (int i=0;i<64;++i)
    bond[(size_t)(ebase+i)*64 + lane] = sb[sw(lane, i)];
}

// gate = sig(atom @ wrW + wrb); num[b] += gate*atom; cnt[b] += 1
__global__ void k_gate(const float* __restrict__ atom, const int* __restrict__ batch,
                       const float* __restrict__ wrW, const float* __restrict__ wrb,
                       float* __restrict__ num, float* __restrict__ cnt){
  int idx = blockIdx.x*256 + threadIdx.x;
  int a = idx >> 6, u = idx & 63;
  const float* ar = atom + (size_t)a*64;
  float acc = wrb[u];
  #pragma unroll
  for (int v=0;v<64;++v) acc += ar[v]*wrW[v*64+u];
  float g = sigf(acc);
  int b = batch[a];
  atomicAdd(&num[b*64+u], g*ar[u]);
  if (u==0) atomicAdd(&cnt[b], 1.0f);
}

// out[g] = silu(vec @ fW1 + fb1) @ fW2 + fb2,  vec = num/max(cnt,1)
__global__ __launch_bounds__(64) void k_final(const float* __restrict__ num, const float* __restrict__ cnt,
                        const float* __restrict__ fW1, const float* __restrict__ fb1,
                        const float* __restrict__ fW2, const float* __restrict__ fb2,
                        float* __restrict__ out){
  int g = blockIdx.x; int u = threadIdx.x;
  float inv = 1.0f / fmaxf(cnt[g], 1.0f);
  float acc = fb1[u];
  #pragma unroll
  for (int v=0;v<64;++v) acc += num[g*64+v]*inv*fW1[v*64+u];
  float p = siluf(acc)*fW2[u];
  #pragma unroll
  for (int off=32; off>0; off>>=1) p += __shfl_down(p, off, 64);
  if (u==0) out[g] = p + fb2[0];
}

extern "C" void kernel_launch(void* const* d_in, const int* in_sizes, int n_in,
                              void* d_out, int out_size, void* d_ws, size_t ws_size,
                              hipStream_t stream){
  const int*   atom_types = (const int*)d_in[0];
  const int*   bai   = (const int*)d_in[1];
  const int*   tbi   = (const int*)d_in[2];
  const int*   batch = (const int*)d_in[3];
  const float* rbf   = (const float*)d_in[4];
  const float* tb    = (const float*)d_in[5];
  const float* emb   = (const float*)d_in[6];
  const float* bW    = (const float*)d_in[7];
  const float* bb    = (const float*)d_in[8];
  const float* tuW   = (const float*)d_in[9];
  const float* tub   = (const float*)d_in[10];
  const float* tfW1  = (const float*)d_in[11];
  const float* tfb1  = (const float*)d_in[12];
  const float* tfW2  = (const float*)d_in[13];
  const float* tfb2  = (const float*)d_in[14];
  const float* gbW1  = (const float*)d_in[15];
  const float* gbb1  = (const float*)d_in[16];
  const float* gbW2  = (const float*)d_in[17];
  const float* gbb2  = (const float*)d_in[18];
  const float* gaW1  = (const float*)d_in[19];
  const float* gab1  = (const float*)d_in[20];
  const float* gaW2  = (const float*)d_in[21];
  const float* gab2  = (const float*)d_in[22];
  const float* wrW   = (const float*)d_in[23];
  const float* wrb   = (const float*)d_in[24];
  const float* fW1   = (const float*)d_in[25];
  const float* fb1   = (const float*)d_in[26];
  const float* fW2   = (const float*)d_in[27];
  const float* fb2   = (const float*)d_in[28];

  char* ws = (char*)d_ws;
  size_t off = 0;
  auto alloc = [&](size_t bytes)->char* {
    char* p = ws + off; off += (bytes + 255) & ~size_t(255); return p;
  };
  float* bond    = (float*)alloc((size_t)E_N*64*4);
  float* agg     = (float*)alloc((size_t)E_N*48*4);
  float* atomA   = (float*)alloc((size_t)A_N*64*4);
  float* atomB   = (float*)alloc((size_t)A_N*64*4);
  float* tuo     = (float*)alloc((size_t)A_N*48*4);
  float* num     = (float*)alloc((size_t)G_N*64*4);
  float* cnt     = (float*)alloc((size_t)G_N*4);
  // CSR (triples grouped by tb0) — built once, reused for all 3 blocks
  int*   tri_offs= (int*)  alloc((size_t)(E_N+1)*4);
  int*   tri_hist= (int*)  alloc((size_t)E_N*4);     // reused as scatter cursor
  int*   tri_perm= (int*)  alloc((size_t)T_N*4);
  int*   tri_ends= (int*)  alloc((size_t)T_N*4);
  int*   scan_sums=(int*)  alloc(4096);

  k_atom_init<<<A_N*64/256, 256, 0, stream>>>(atom_types, emb, atomA);
  k_bond_init<<<E_N*64/256, 256, 0, stream>>>(rbf, bW, bb, bond);

  // build triple CSR (topology is constant across the 3 blocks)
  hipMemsetAsync(tri_hist, 0, (size_t)E_N*4, stream);
  k_hist_tri<<<(T_N+255)/256, 256, 0, stream>>>(tbi, tri_hist);
  k_scan1<<<TRI_CHUNKS, 256, 0, stream>>>(tri_hist, tri_offs, scan_sums, E_N);
  k_scan2<<<1, 64, 0, stream>>>(scan_sums, TRI_CHUNKS, tri_offs + E_N);
  k_scan3<<<(E_N+255)/256, 256, 0, stream>>>(tri_offs, scan_sums, E_N);
  hipMemsetAsync(tri_hist, 0, (size_t)E_N*4, stream);   // cursor
  k_scatter_tri<<<(T_N+255)/256, 256, 0, stream>>>(tbi, bai, tri_offs, tri_hist,
                                                   tri_perm, tri_ends);

  hipMemsetAsync(num, 0, G_N*64*4, stream);
  hipMemsetAsync(cnt, 0, G_N*4, stream);

  float* cur = atomA; float* nxt = atomB;
  for (int i=0;i<NB;++i){
    k_tu<<<A_N*48/256, 256, 0, stream>>>(cur, tuW + (size_t)i*64*48, tub + (size_t)i*48, tuo);
    k_triple_s<<<E_N*12/256, 256, 0, stream>>>(tb, tri_perm, tri_ends, tuo, tri_offs, agg);
    hipMemcpyAsync(nxt, cur, (size_t)A_N*64*4, hipMemcpyDeviceToDevice, stream);
    k_edge<<<E_N/128, 128, 0, stream>>>(agg, bond, cur, nxt, bai,
        tfW1 + (size_t)i*48*64, tfb1 + (size_t)i*64,
        tfW2 + (size_t)i*48*64, tfb2 + (size_t)i*64,
        gbW1 + (size_t)i*192*64, gbb1 + (size_t)i*64,
        gbW2 + (size_t)i*192*64, gbb2 + (size_t)i*64,
        gaW1 + (size_t)i*64*64, gab1 + (size_t)i*64,
        gaW2 + (size_t)i*64*64, gab2 + (size_t)i*64);
    float* t2 = cur; cur = nxt; nxt = t2;
  }
  k_gate<<<A_N*64/256, 256, 0, stream>>>(cur, batch, wrW, wrb, num, cnt);
  k_final<<<G_N, 64, 0, stream>>>(num, cnt, fW1, fb1, fW2, fb2, (float*)d_out);
}

// Round 3
// 10503.680 us; speedup vs baseline: 1.5653x; 1.5653x over previous
//
#include <hip/hip_runtime.h>
#include <cstdint>

#define A_N 50000
#define E_N 1200000
#define T_N 2000000
#define G_N 500
#define U_N 64
#define RBF_N 48
#define NB 3

#define SCAN_CHUNK 2048  // 256 threads * 8 elems
#define TRI_CHUNKS ((E_N + SCAN_CHUNK - 1) / SCAN_CHUNK)
#define ATM_CHUNKS ((A_N + SCAN_CHUNK - 1) / SCAN_CHUNK)

__device__ __forceinline__ float sigf(float x){ return 1.0f/(1.0f+__expf(-x)); }
__device__ __forceinline__ float siluf(float x){ return x/(1.0f+__expf(-x)); }

// LDS bond tile layout: transposed + XOR swizzle. k = feature (0..63), e = edge-in-wave.
__device__ __forceinline__ int sw(int k, int e){ return k*64 + (e ^ (k & 31)); }

// atom = emb[atom_types]   (A x 64)
__global__ void k_atom_init(const int* __restrict__ types, const float* __restrict__ emb,
                            float* __restrict__ atom){
  int idx = blockIdx.x*256 + threadIdx.x;
  int a = idx >> 6, u = idx & 63;
  atom[idx] = emb[types[a]*U_N + u];
}

// bond = silu(rbf @ bW + bb)   (E x 64)
__global__ void k_bond_init(const float* __restrict__ rbf, const float* __restrict__ bW,
                            const float* __restrict__ bb, float* __restrict__ bond){
  int idx = blockIdx.x*256 + threadIdx.x;
  int e = idx >> 6, u = idx & 63;
  float acc = bb[u];
  acc += rbf[e*3+0]*bW[0*U_N+u];
  acc += rbf[e*3+1]*bW[1*U_N+u];
  acc += rbf[e*3+2]*bW[2*U_N+u];
  bond[idx] = siluf(acc);
}

// ---- generic CSR-build helpers (counting sort); topology fixed across blocks ----

// per-chunk exclusive scan (256 thr x 8 elems), chunk totals -> sums[]
__global__ void k_scan1(const int* __restrict__ in, int* __restrict__ out,
                        int* __restrict__ sums, int n){
  __shared__ int sdata[256];
  int base = blockIdx.x*SCAN_CHUNK;
  int tid = threadIdx.x;
  int v[8]; int s = 0;
  #pragma unroll
  for (int k=0;k<8;++k){ int i = base + tid*8 + k; v[k] = (i<n) ? in[i] : 0; s += v[k]; }
  sdata[tid] = s; __syncthreads();
  #pragma unroll
  for (int off=1; off<256; off<<=1){
    int t = (tid>=off) ? sdata[tid-off] : 0;
    __syncthreads();
    sdata[tid] += t;
    __syncthreads();
  }
  int run = (tid==0) ? 0 : sdata[tid-1];
  if (tid==255) sums[blockIdx.x] = sdata[255];
  #pragma unroll
  for (int k=0;k<8;++k){ int i = base + tid*8 + k; if (i<n) out[i] = run; run += v[k]; }
}

// serial exclusive scan of chunk sums (runs once, few hundred elems); total -> *total
__global__ void k_scan2(int* __restrict__ sums, int nchunks, int* __restrict__ total){
  if (blockIdx.x==0 && threadIdx.x==0){
    int acc = 0;
    for (int c=0;c<nchunks;++c){ int v = sums[c]; sums[c] = acc; acc += v; }
    *total = acc;
  }
}

__global__ void k_scan3(int* __restrict__ out, const int* __restrict__ sums, int n){
  int i = blockIdx.x*256 + threadIdx.x;
  if (i < n) out[i] += sums[i / SCAN_CHUNK];
}

// ---- triple CSR (grouped by tb0) ----
__global__ void k_hist_tri(const int* __restrict__ tbi, int* __restrict__ hist){
  int t = blockIdx.x*256 + threadIdx.x;
  if (t < T_N) atomicAdd(&hist[tbi[2*t]], 1);
}

// scatter: perm[pos] = t, ends[pos] = dst[tb1[t]], grouped by tb0
__global__ void k_scatter_tri(const int* __restrict__ tbi, const int* __restrict__ bai,
                              const int* __restrict__ offs, int* __restrict__ cursor,
                              int* __restrict__ perm, int* __restrict__ ends){
  int t = blockIdx.x*256 + threadIdx.x;
  if (t < T_N){
    int b = tbi[2*t];
    int pos = offs[b] + atomicAdd(&cursor[b], 1);
    perm[pos] = t;
    ends[pos] = bai[2*tbi[2*t+1]+1];
  }
}

// ---- edge CSR (grouped by dst atom) ----
__global__ void k_hist_e(const int* __restrict__ bai, int* __restrict__ hist){
  int e = blockIdx.x*256 + threadIdx.x;
  if (e < E_N) atomicAdd(&hist[bai[2*e+1]], 1);
}

__global__ void k_scatter_e(const int* __restrict__ bai, const int* __restrict__ offs,
                            int* __restrict__ cursor, int* __restrict__ eidx){
  int e = blockIdx.x*256 + threadIdx.x;
  if (e < E_N){
    int d = bai[2*e+1];
    int pos = offs[d] + atomicAdd(&cursor[d], 1);
    eidx[pos] = e;
  }
}

// agg[e] = sum over triples with tb0==e of three_basis[t] * tuo[end_atom[t]]
// atomic-free segmented reduction; thread per (e, q), q = float4 chunk of the 48-wide row.
__global__ void k_triple_s(const float* __restrict__ tb, const int* __restrict__ perm,
                           const int* __restrict__ ends, const float* __restrict__ tuo,
                           const int* __restrict__ offs, float* __restrict__ agg){
  int idx = blockIdx.x*256 + threadIdx.x;      // E_N*12 total, divisible by 256
  int e = idx / 12, q = idx - e*12;
  int j0 = offs[e], j1 = offs[e+1];
  float4 acc = make_float4(0.f,0.f,0.f,0.f);
  for (int j=j0; j<j1; ++j){
    int t  = perm[j];
    int ea = ends[j];
    float4 b = *(const float4*)(tb  + (size_t)t *48 + q*4);
    float4 w = *(const float4*)(tuo + (size_t)ea*48 + q*4);
    acc.x = fmaf(b.x, w.x, acc.x);
    acc.y = fmaf(b.y, w.y, acc.y);
    acc.z = fmaf(b.z, w.z, acc.z);
    acc.w = fmaf(b.w, w.w, acc.w);
  }
  *(float4*)(agg + (size_t)e*48 + q*4) = acc;
}

// tuo = sigmoid(atom @ tuW + tub)   (A x 48)
__global__ void k_tu(const float* __restrict__ atom, const float* __restrict__ tuW,
                     const float* __restrict__ tub, float* __restrict__ tuo){
  int idx = blockIdx.x*256 + threadIdx.x;
  int a = idx / 48, r = idx - a*48;
  const float* ar = atom + a*U_N;
  float acc = tub[r];
  #pragma unroll
  for (int v=0; v<U_N; ++v) acc += ar[v]*tuW[v*48+r];
  tuo[idx] = sigf(acc);
}

// accumulate an 8-wide K chunk into 32 outputs (x2 matrices). c stays in VGPRs
// (k fully unrolled); weight addresses are wave-uniform -> scalar loads broadcast.
__device__ __forceinline__ void accum8(const float* __restrict__ W1, const float* __restrict__ W2,
                                       int kb, int ub, const float (&c)[8],
                                       float (&acc1)[32], float (&acc2)[32]){
  #pragma unroll
  for (int k=0;k<8;++k){
    const float cv = c[k];
    const float* w1 = W1 + (size_t)(kb+k)*64 + ub;
    const float* w2 = W2 + (size_t)(kb+k)*64 + ub;
    #pragma unroll
    for (int u=0;u<32;++u){
      acc1[u] = fmaf(cv, w1[u], acc1[u]);
      acc2[u] = fmaf(cv, w2[u], acc2[u]);
    }
  }
}

// Fused per-edge: bond += tf(agg); bond += gb(cat); msg = ga(bond) -> msgbuf (dense, no atomics)
__global__ __launch_bounds__(128) void k_edge(
    const float* __restrict__ agg, float* __restrict__ bond,
    const float* __restrict__ atomc, float* __restrict__ msgbuf,
    const int* __restrict__ bai,
    const float* __restrict__ tfW1, const float* __restrict__ tfb1,
    const float* __restrict__ tfW2, const float* __restrict__ tfb2,
    const float* __restrict__ gbW1, const float* __restrict__ gbb1,
    const float* __restrict__ gbW2, const float* __restrict__ gbb2,
    const float* __restrict__ gaW1, const float* __restrict__ gab1,
    const float* __restrict__ gaW2, const float* __restrict__ gab2)
{
  __shared__ float s_all[2*64*64];
  const int lane  = threadIdx.x & 63;
  const int w     = threadIdx.x >> 6;
  float* sb = s_all + w*4096;
  const int ebase = blockIdx.x*128 + w*64;
  const int e     = ebase + lane;

  // stage bond tile: coalesced 256B row reads, swizzled transposed LDS writes
  #pragma unroll 1
  for (int i=0;i<64;++i)
    sb[sw(lane, i)] = bond[(size_t)(ebase+i)*64 + lane];

  const float* aggr = agg + (size_t)e*48;

  // ---- phase 1: tf ----
  #pragma unroll 1
  for (int ug=0; ug<2; ++ug){
    const int ub = ug*32;
    float acc1[32], acc2[32];
    #pragma unroll
    for (int u=0;u<32;++u){ acc1[u] = tfb1[ub+u]; acc2[u] = tfb2[ub+u]; }
    #pragma unroll 1
    for (int kc=0;kc<6;++kc){
      float c[8];
      const float4* p = (const float4*)(aggr + kc*8);
      float4 v0 = p[0], v1 = p[1];
      c[0]=v0.x;c[1]=v0.y;c[2]=v0.z;c[3]=v0.w;c[4]=v1.x;c[5]=v1.y;c[6]=v1.z;c[7]=v1.w;
      accum8(tfW1, tfW2, kc*8, ub, c, acc1, acc2);
    }
    #pragma unroll
    for (int u=0;u<32;++u)
      sb[sw(ub+u, lane)] += siluf(acc1[u])*sigf(acc2[u]);
  }

  // ---- phase 2: gb (cat = [atom[src], atom[dst], bond_new]) ----
  const int src = bai[2*e], dst = bai[2*e+1];
  const float* srow = atomc + (size_t)src*64;
  const float* drow = atomc + (size_t)dst*64;
  float res0[32];                       // ug0 results stashed so ug1 still sees old bond in LDS
  #pragma unroll
  for (int ug=0; ug<2; ++ug){
    const int ub = ug*32;
    float acc1[32], acc2[32];
    #pragma unroll
    for (int u=0;u<32;++u){ acc1[u] = gbb1[ub+u]; acc2[u] = gbb2[ub+u]; }
    // segments 0,1: gathered atom rows (k 0..63 and 64..127)
    #pragma unroll 1
    for (int s=0;s<2;++s){
      const float* row = s ? drow : srow;
      const int kb = s*64;
      #pragma unroll 1
      for (int kc=0;kc<8;++kc){
        float c[8];
        const float4* p = (const float4*)(row + kc*8);
        float4 v0 = p[0], v1 = p[1];
        c[0]=v0.x;c[1]=v0.y;c[2]=v0.z;c[3]=v0.w;c[4]=v1.x;c[5]=v1.y;c[6]=v1.z;c[7]=v1.w;
        accum8(gbW1, gbW2, kb+kc*8, ub, c, acc1, acc2);
      }
    }
    // segment 2: bond_new from LDS (k 128..191)
    #pragma unroll 1
    for (int kc=0;kc<8;++kc){
      float c[8];
      #pragma unroll
      for (int j=0;j<8;++j) c[j] = sb[sw(kc*8+j, lane)];
      accum8(gbW1, gbW2, 128+kc*8, ub, c, acc1, acc2);
    }
    if (ug==0){
      #pragma unroll
      for (int u=0;u<32;++u)
        res0[u] = sb[sw(u, lane)] + siluf(acc1[u])*sigf(acc2[u]);
    } else {
      #pragma unroll
      for (int u=0;u<32;++u)
        sb[sw(32+u, lane)] += siluf(acc1[u])*sigf(acc2[u]);
      #pragma unroll
      for (int u=0;u<32;++u)
        sb[sw(u, lane)] = res0[u];
    }
  }

  // ---- phase 3: ga -> msg -> dense msgbuf row (contiguous float4 stores, no atomics) ----
  float* mrow = msgbuf + (size_t)e*64;
  #pragma unroll 1
  for (int ug=0; ug<2; ++ug){
    const int ub = ug*32;
    float acc1[32], acc2[32];
    #pragma unroll
    for (int u=0;u<32;++u){ acc1[u] = gab1[ub+u]; acc2[u] = gab2[ub+u]; }
    #pragma unroll 1
    for (int kc=0;kc<8;++kc){
      float c[8];
      #pragma unroll
      for (int j=0;j<8;++j) c[j] = sb[sw(kc*8+j, lane)];
      accum8(gaW1, gaW2, kc*8, ub, c, acc1, acc2);
    }
    #pragma unroll
    for (int u4=0;u4<8;++u4){
      float4 mv;
      mv.x = siluf(acc1[u4*4+0])*sigf(acc2[u4*4+0]);
      mv.y = siluf(acc1[u4*4+1])*sigf(acc2[u4*4+1]);
      mv.z = siluf(acc1[u4*4+2])*sigf(acc2[u4*4+2]);
      mv.w = siluf(acc1[u4*4+3])*sigf(acc2[u4*4+3]);
      *(float4*)(mrow + ub + u4*4) = mv;
    }
  }

  // final bond store: coalesced
  #pragma unroll 1
  for (int i=0;i<64;++i)
    bond[(size_t)(ebase+i)*64 + lane] = sb[sw(lane, i)];
}

// atomn[a] = atomc[a] + sum over incoming edges (CSR by dst) of msgbuf rows.
// one wave per atom; 256 B coalesced row reads, index loads broadcast.
__global__ void k_msg_agg(const float* __restrict__ msgbuf, const int* __restrict__ eidx,
                          const int* __restrict__ offs, const float* __restrict__ atomc,
                          float* __restrict__ atomn){
  int idx = blockIdx.x*256 + threadIdx.x;   // A_N*64
  int a = idx >> 6, u = idx & 63;
  int j0 = offs[a], j1 = offs[a+1];
  float s = atomc[idx];
  for (int j=j0; j<j1; ++j)
    s += msgbuf[(size_t)eidx[j]*64 + u];
  atomn[idx] = s;
}

// gate = sig(atom @ wrW + wrb); num[b] += gate*atom; cnt[b] += 1
__global__ void k_gate(const float* __restrict__ atom, const int* __restrict__ batch,
                       const float* __restrict__ wrW, const float* __restrict__ wrb,
                       float* __restrict__ num, float* __restrict__ cnt){
  int idx = blockIdx.x*256 + threadIdx.x;
  int a = idx >> 6, u = idx & 63;
  const float* ar = atom + (size_t)a*64;
  float acc = wrb[u];
  #pragma unroll
  for (int v=0;v<64;++v) acc += ar[v]*wrW[v*64+u];
  float g = sigf(acc);
  int b = batch[a];
  atomicAdd(&num[b*64+u], g*ar[u]);
  if (u==0) atomicAdd(&cnt[b], 1.0f);
}

// out[g] = silu(vec @ fW1 + fb1) @ fW2 + fb2,  vec = num/max(cnt,1)
__global__ __launch_bounds__(64) void k_final(const float* __restrict__ num, const float* __restrict__ cnt,
                        const float* __restrict__ fW1, const float* __restrict__ fb1,
                        const float* __restrict__ fW2, const float* __restrict__ fb2,
                        float* __restrict__ out){
  int g = blockIdx.x; int u = threadIdx.x;
  float inv = 1.0f / fmaxf(cnt[g], 1.0f);
  float acc = fb1[u];
  #pragma unroll
  for (int v=0;v<64;++v) acc += num[g*64+v]*inv*fW1[v*64+u];
  float p = siluf(acc)*fW2[u];
  #pragma unroll
  for (int off=32; off>0; off>>=1) p += __shfl_down(p, off, 64);
  if (u==0) out[g] = p + fb2[0];
}

extern "C" void kernel_launch(void* const* d_in, const int* in_sizes, int n_in,
                              void* d_out, int out_size, void* d_ws, size_t ws_size,
                              hipStream_t stream){
  const int*   atom_types = (const int*)d_in[0];
  const int*   bai   = (const int*)d_in[1];
  const int*   tbi   = (const int*)d_in[2];
  const int*   batch = (const int*)d_in[3];
  const float* rbf   = (const float*)d_in[4];
  const float* tb    = (const float*)d_in[5];
  const float* emb   = (const float*)d_in[6];
  const float* bW    = (const float*)d_in[7];
  const float* bb    = (const float*)d_in[8];
  const float* tuW   = (const float*)d_in[9];
  const float* tub   = (const float*)d_in[10];
  const float* tfW1  = (const float*)d_in[11];
  const float* tfb1  = (const float*)d_in[12];
  const float* tfW2  = (const float*)d_in[13];
  const float* tfb2  = (const float*)d_in[14];
  const float* gbW1  = (const float*)d_in[15];
  const float* gbb1  = (const float*)d_in[16];
  const float* gbW2  = (const float*)d_in[17];
  const float* gbb2  = (const float*)d_in[18];
  const float* gaW1  = (const float*)d_in[19];
  const float* gab1  = (const float*)d_in[20];
  const float* gaW2  = (const float*)d_in[21];
  const float* gab2  = (const float*)d_in[22];
  const float* wrW   = (const float*)d_in[23];
  const float* wrb   = (const float*)d_in[24];
  const float* fW1   = (const float*)d_in[25];
  const float* fb1   = (const float*)d_in[26];
  const float* fW2   = (const float*)d_in[27];
  const float* fb2   = (const float*)d_in[28];

  char* ws = (char*)d_ws;
  size_t off = 0;
  auto alloc = [&](size_t bytes)->char* {
    char* p = ws + off; off += (bytes + 255) & ~size_t(255); return p;
  };
  float* bond    = (float*)alloc((size_t)E_N*64*4);
  float* agg     = (float*)alloc((size_t)E_N*48*4);
  float* msgbuf  = (float*)alloc((size_t)E_N*64*4);
  float* atomA   = (float*)alloc((size_t)A_N*64*4);
  float* atomB   = (float*)alloc((size_t)A_N*64*4);
  float* tuo     = (float*)alloc((size_t)A_N*48*4);
  float* num     = (float*)alloc((size_t)G_N*64*4);
  float* cnt     = (float*)alloc((size_t)G_N*4);
  // triple CSR (grouped by tb0)
  int*   tri_offs= (int*)  alloc((size_t)(E_N+1)*4);
  int*   tri_hist= (int*)  alloc((size_t)E_N*4);     // reused as scatter cursor
  int*   tri_perm= (int*)  alloc((size_t)T_N*4);
  int*   tri_ends= (int*)  alloc((size_t)T_N*4);
  // edge CSR (grouped by dst)
  int*   e_offs  = (int*)  alloc((size_t)(A_N+1)*4);
  int*   e_hist  = (int*)  alloc((size_t)A_N*4);     // reused as scatter cursor
  int*   e_idx   = (int*)  alloc((size_t)E_N*4);
  int*   scan_sums=(int*)  alloc(4096);

  k_atom_init<<<A_N*64/256, 256, 0, stream>>>(atom_types, emb, atomA);
  k_bond_init<<<E_N*64/256, 256, 0, stream>>>(rbf, bW, bb, bond);

  // build triple CSR (topology constant across blocks)
  hipMemsetAsync(tri_hist, 0, (size_t)E_N*4, stream);
  k_hist_tri<<<(T_N+255)/256, 256, 0, stream>>>(tbi, tri_hist);
  k_scan1<<<TRI_CHUNKS, 256, 0, stream>>>(tri_hist, tri_offs, scan_sums, E_N);
  k_scan2<<<1, 64, 0, stream>>>(scan_sums, TRI_CHUNKS, tri_offs + E_N);
  k_scan3<<<(E_N+255)/256, 256, 0, stream>>>(tri_offs, scan_sums, E_N);
  hipMemsetAsync(tri_hist, 0, (size_t)E_N*4, stream);   // cursor
  k_scatter_tri<<<(T_N+255)/256, 256, 0, stream>>>(tbi, bai, tri_offs, tri_hist,
                                                   tri_perm, tri_ends);

  // build edge CSR by dst (topology constant across blocks)
  hipMemsetAsync(e_hist, 0, (size_t)A_N*4, stream);
  k_hist_e<<<(E_N+255)/256, 256, 0, stream>>>(bai, e_hist);
  k_scan1<<<ATM_CHUNKS, 256, 0, stream>>>(e_hist, e_offs, scan_sums, A_N);
  k_scan2<<<1, 64, 0, stream>>>(scan_sums, ATM_CHUNKS, e_offs + A_N);
  k_scan3<<<(A_N+255)/256, 256, 0, stream>>>(e_offs, scan_sums, A_N);
  hipMemsetAsync(e_hist, 0, (size_t)A_N*4, stream);     // cursor
  k_scatter_e<<<(E_N+255)/256, 256, 0, stream>>>(bai, e_offs, e_hist, e_idx);

  hipMemsetAsync(num, 0, G_N*64*4, stream);
  hipMemsetAsync(cnt, 0, G_N*4, stream);

  float* cur = atomA; float* nxt = atomB;
  for (int i=0;i<NB;++i){
    k_tu<<<A_N*48/256, 256, 0, stream>>>(cur, tuW + (size_t)i*64*48, tub + (size_t)i*48, tuo);
    k_triple_s<<<E_N*12/256, 256, 0, stream>>>(tb, tri_perm, tri_ends, tuo, tri_offs, agg);
    k_edge<<<E_N/128, 128, 0, stream>>>(agg, bond, cur, msgbuf, bai,
        tfW1 + (size_t)i*48*64, tfb1 + (size_t)i*64,
        tfW2 + (size_t)i*48*64, tfb2 + (size_t)i*64,
        gbW1 + (size_t)i*192*64, gbb1 + (size_t)i*64,
        gbW2 + (size_t)i*192*64, gbb2 + (size_t)i*64,
        gaW1 + (size_t)i*64*64, gab1 + (size_t)i*64,
        gaW2 + (size_t)i*64*64, gab2 + (size_t)i*64);
    k_msg_agg<<<A_N*64/256, 256, 0, stream>>>(msgbuf, e_idx, e_offs, cur, nxt);
    float* t2 = cur; cur = nxt; nxt = t2;
  }
  k_gate<<<A_N*64/256, 256, 0, stream>>>(cur, batch, wrW, wrb, num, cnt);
  k_final<<<G_N, 64, 0, stream>>>(num, cnt, fW1, fb1, fW2, fb2, (float*)d_out);
}